// Round 8
// baseline (103.063 us; speedup 1.0000x reference)
//
#include <hip/hip_runtime.h>
#include <math.h>

#define DIM 128
#define N_PTS 512
#define K_NEIGH 16
#define POS_HID 64
#define ATTN_HID 512

typedef __attribute__((ext_vector_type(8))) short short8;
typedef __attribute__((ext_vector_type(4))) float f32x4;
typedef unsigned short us;
typedef unsigned long long ull;

__device__ __forceinline__ us f2b(float f) {
    unsigned int u = __builtin_bit_cast(unsigned int, f);
    u += 0x7fffu + ((u >> 16) & 1u);          // RNE
    return (us)(u >> 16);
}

__device__ __forceinline__ ull shflx64(ull v, int m) {
    int lo = __shfl_xor((int)(unsigned int)v, m);
    int hi = __shfl_xor((int)(unsigned int)(v >> 32), m);
    return ((ull)(unsigned int)hi << 32) | (unsigned int)lo;
}

// ---------------------------------------------------------------------------
// Pack weights (fp32) -> bf16 B-fragment order for mfma_16x16x32_bf16:
// B[k][n] -> lane l=(k/8%4)*16+(n%16), elem j=k%8, frag=(ks*NT+nt);
// packed[(frag*64+l)*8+j].  p0=wqkv(128x384), p1=aw1(128x512),
// p2=aw2(512x128), p3=pw2(64x128).   [R2-proven]
// ---------------------------------------------------------------------------
__global__ void pack_kernel(const float* __restrict__ wqkv,
                            const float* __restrict__ aw1,
                            const float* __restrict__ aw2,
                            const float* __restrict__ pw2,
                            us* __restrict__ p0, us* __restrict__ p1,
                            us* __restrict__ p2, us* __restrict__ p3) {
    int t = blockIdx.x * 256 + threadIdx.x;
    if (t < 49152) {                        // wqkv: nt 0..23, ks 0..3
        int j = t & 7, l = (t >> 3) & 63, rem = t >> 9;
        int nt = rem % 24, ks = rem / 24;
        int k = ks * 32 + (l >> 4) * 8 + j, n = nt * 16 + (l & 15);
        p0[t] = f2b(wqkv[k * 384 + n]);
    } else if (t < 114688) {                // aw1: ks 0..3, nt 0..31
        int u = t - 49152;
        int j = u & 7, l = (u >> 3) & 63, nt = (u >> 9) & 31, ks = u >> 14;
        int k = ks * 32 + (l >> 4) * 8 + j, n = nt * 16 + (l & 15);
        p1[u] = f2b(aw1[k * ATTN_HID + n]);
    } else if (t < 180224) {                // aw2: ch 0..15, nt 0..7
        int u = t - 114688;
        int j = u & 7, l = (u >> 3) & 63, nt = (u >> 9) & 7, ch = u >> 12;
        int k = ch * 32 + (l >> 4) * 8 + j, n = nt * 16 + (l & 15);
        p2[u] = f2b(aw2[k * DIM + n]);
    } else if (t < 188416) {                // pw2: ks 0..1, nt 0..7
        int u = t - 180224;
        int j = u & 7, l = (u >> 3) & 63, nt = (u >> 9) & 7, ks = u >> 12;
        int k = ks * 32 + (l >> 4) * 8 + j, n = nt * 16 + (l & 15);
        p3[u] = f2b(pw2[k * DIM + n]);
    }
}

// ---------------------------------------------------------------------------
// qkv via MFMA: 64 blocks x 512 thr (8 waves). [R7-proven, unchanged]
// ---------------------------------------------------------------------------
__global__ __launch_bounds__(512)
void qkv_mfma_kernel(const float* __restrict__ x,
                     const us* __restrict__ p0,
                     float* __restrict__ qkv) {
    __shared__ __align__(16) us xA[16][136];
    const int tid = threadIdx.x;
    const int w = tid >> 6, lane = tid & 63, quad = lane >> 4, lq = lane & 15;
    const int n0 = blockIdx.x * 16;
    const int b = n0 >> 9, nn = n0 & (N_PTS - 1);
#pragma unroll
    for (int rr = 0; rr < 4; ++rr) {
        int id = rr * 512 + tid;
        int d = id >> 4, i = id & 15;
        xA[i][d] = f2b(x[(size_t)(b * DIM + d) * N_PTS + nn + i]);
    }
    __syncthreads();
    short8 a[4];
#pragma unroll
    for (int ks = 0; ks < 4; ++ks)
        a[ks] = *(const short8*)&xA[lq][ks * 32 + quad * 8];
#pragma unroll
    for (int i = 0; i < 3; ++i) {
        int nt = w * 3 + i;
        f32x4 acc = {0.f, 0.f, 0.f, 0.f};
#pragma unroll
        for (int ks = 0; ks < 4; ++ks) {
            const short8 bf = *(const short8*)(p0 + (size_t)((ks * 24 + nt) * 64 + lane) * 8);
            acc = __builtin_amdgcn_mfma_f32_16x16x32_bf16(a[ks], bf, acc, 0, 0, 0);
        }
#pragma unroll
        for (int r = 0; r < 4; ++r)
            qkv[(size_t)(n0 + quad * 4 + r) * 384 + nt * 16 + lq] = acc[r];
    }
}

// ---------------------------------------------------------------------------
// Fused attention, ch-split: block = 128 thr = 2 waves = ONE point.
// Wave s handles hidden chunks ch in [8s, 8s+8): layer1's N-split equals
// layer2's K-split, so the split adds no weight traffic. Both waves run
// topk/posMLP/pe/hin independently (identical deterministic results, own LDS
// buffers). Single cross-wave exchange: s=0's c2 partial through c2s behind
// one __syncthreads; s=1 adds, gathers vg, softmax, store.
// 1024 blocks -> 4 blocks/CU = 2 waves/SIMD (TLP) and per-wave serial ch-work
// halved; the 2 waves of a block share chunk weights via L1.
// ab2 skipped: softmax over k is invariant to a per-channel constant.
// ---------------------------------------------------------------------------
__global__ __launch_bounds__(128, 2)
void attn_fused_kernel(const float* __restrict__ pos,
                       const float* __restrict__ qkv,
                       const float* __restrict__ pw1,
                       const float* __restrict__ pb1,
                       const float* __restrict__ pb2,
                       const us* __restrict__ p1,
                       const us* __restrict__ p2,
                       const us* __restrict__ p3,
                       const float* __restrict__ ab1,
                       float* __restrict__ out) {
    __shared__ __align__(16) us hinA[2][16][136];   //  8.5 KB, per-wave
    __shared__ __align__(16) us h1s[2][16][40];     //  2.5 KB, per-wave
    __shared__ float c2s[32][66];                   //  8.25 KB exchange
    __shared__ int nbrs[2][16];                     //  128 B, per-wave

    const int tid = threadIdx.x;
    const int s = tid >> 6, lane = tid & 63, quad = lane >> 4, lq = lane & 15;
    const int g = blockIdx.x, b = g >> 9, n = g & (N_PTS - 1);

    float qvr[8], pb2r[8];
#pragma unroll
    for (int nt = 0; nt < 8; ++nt) {
        qvr[nt]  = qkv[(size_t)g * 384 + nt * 16 + lq];
        pb2r[nt] = pb2[nt * 16 + lq];
    }

    // ---- top-16: u64 key = (dist_bits<<32)|j, butterfly min [R5-exact] ----
    {
        const float pix = pos[g * 3 + 0], piy = pos[g * 3 + 1], piz = pos[g * 3 + 2];
        float d2[8];
#pragma unroll
        for (int rr = 0; rr < 8; ++rr) {
            int j = rr * 64 + lane;
            float dx = pix - pos[(b * N_PTS + j) * 3 + 0];
            float dy = piy - pos[(b * N_PTS + j) * 3 + 1];
            float dz = piz - pos[(b * N_PTS + j) * 3 + 2];
            d2[rr] = dx * dx + dy * dy + dz * dz;
        }
        for (int r = 0; r < K_NEIGH; ++r) {
            ull key = ~0ULL;
#pragma unroll
            for (int rr = 0; rr < 8; ++rr) {
                unsigned int fb = __builtin_bit_cast(unsigned int, d2[rr]);
                ull k2 = ((ull)fb << 32) | (unsigned int)(rr * 64 + lane);
                key = k2 < key ? k2 : key;
            }
#pragma unroll
            for (int off = 32; off > 0; off >>= 1) {
                ull o = shflx64(key, off);
                key = o < key ? o : key;
            }
            unsigned int jw = (unsigned int)key;      // uniform post-butterfly
            if (lane == 0) nbrs[s][r] = (int)jw;
            if (lane == (int)(jw & 63)) d2[jw >> 6] = __builtin_inff();
        }
    }

    // ---- pos-MLP hidden -> A-frags (k = ks*32 + quad*8 + jj) ----
    short8 pha[2];
    {
        const int jn = nbrs[s][lq];
        float rx = pos[g * 3 + 0] - pos[(b * N_PTS + jn) * 3 + 0];
        float ry = pos[g * 3 + 1] - pos[(b * N_PTS + jn) * 3 + 1];
        float rz = pos[g * 3 + 2] - pos[(b * N_PTS + jn) * 3 + 2];
#pragma unroll
        for (int ks = 0; ks < 2; ++ks) {
            short8 f;
#pragma unroll
            for (int jj = 0; jj < 8; ++jj) {
                int c = ks * 32 + quad * 8 + jj;
                float h = rx * pw1[c] + ry * pw1[64 + c] + rz * pw1[128 + c] + pb1[c];
                f[jj] = (short)f2b(fmaxf(h, 0.f));
            }
            pha[ks] = f;
        }
    }

    // ---- pe = ph @ pw2 + pb2 (M=16,K=64,N=128) ----
    f32x4 pe[8];
#pragma unroll
    for (int nt = 0; nt < 8; ++nt) {
        const short8 b0 = *(const short8*)(p3 + (size_t)((0 * 8 + nt) * 64 + lane) * 8);
        const short8 b1 = *(const short8*)(p3 + (size_t)((1 * 8 + nt) * 64 + lane) * 8);
        f32x4 acc = {0.f, 0.f, 0.f, 0.f};
        acc = __builtin_amdgcn_mfma_f32_16x16x32_bf16(pha[0], b0, acc, 0, 0, 0);
        acc = __builtin_amdgcn_mfma_f32_16x16x32_bf16(pha[1], b1, acc, 0, 0, 0);
#pragma unroll
        for (int r = 0; r < 4; ++r) pe[nt][r] = acc[r] + pb2r[nt];
    }

    // ---- hin = q_i - k_j + pe -> own hinA (bf16 A-layout); vg deferred ----
    int jr[4];
#pragma unroll
    for (int r = 0; r < 4; ++r) jr[r] = nbrs[s][quad * 4 + r];
#pragma unroll
    for (int nt = 0; nt < 8; ++nt) {
        int d = nt * 16 + lq;
#pragma unroll
        for (int r = 0; r < 4; ++r) {
            const float* kv = qkv + (size_t)(b * N_PTS + jr[r]) * 384;
            hinA[s][quad * 4 + r][d] = f2b(qvr[nt] - kv[128 + d] + pe[nt][r]);
        }
    }

    // ---- this wave's 8 chunks: layer1 + layer2, double-buffered weights ----
    short8 a1f[4];
#pragma unroll
    for (int ks = 0; ks < 4; ++ks)
        a1f[ks] = *(const short8*)&hinA[s][lq][ks * 32 + quad * 8];

    f32x4 c2[8];
#pragma unroll
    for (int nt = 0; nt < 8; ++nt) c2[nt] = (f32x4){0.f, 0.f, 0.f, 0.f};

    const int ch0 = s * 8;
    short8 p1f[2][2][4];   // [buf][t][ks]
    short8 p2f[2][8];      // [buf][nt2]
#pragma unroll
    for (int t = 0; t < 2; ++t)
#pragma unroll
        for (int ks = 0; ks < 4; ++ks)
            p1f[0][t][ks] = *(const short8*)(p1 + (size_t)(((ks << 5) + ch0 * 2 + t) * 64 + lane) * 8);
#pragma unroll
    for (int nt2 = 0; nt2 < 8; ++nt2)
        p2f[0][nt2] = *(const short8*)(p2 + (size_t)((ch0 * 8 + nt2) * 64 + lane) * 8);

#pragma unroll
    for (int cc = 0; cc < 8; ++cc) {
        const int ch = ch0 + cc;
        const int cur = cc & 1, nxt = cur ^ 1;
        if (cc < 7) {                       // prefetch next chunk's layer1 wts
#pragma unroll
            for (int t = 0; t < 2; ++t)
#pragma unroll
                for (int ks = 0; ks < 4; ++ks)
                    p1f[nxt][t][ks] = *(const short8*)(p1 + (size_t)(((ks << 5) + (ch + 1) * 2 + t) * 64 + lane) * 8);
        }
#pragma unroll
        for (int t = 0; t < 2; ++t) {
            int nt = ch * 2 + t;
            f32x4 acc = {0.f, 0.f, 0.f, 0.f};
#pragma unroll
            for (int ks = 0; ks < 4; ++ks)
                acc = __builtin_amdgcn_mfma_f32_16x16x32_bf16(a1f[ks], p1f[cur][t][ks], acc, 0, 0, 0);
            float bias = ab1[nt * 16 + lq];
#pragma unroll
            for (int r = 0; r < 4; ++r)
                h1s[s][quad * 4 + r][t * 16 + lq] = f2b(fmaxf(acc[r] + bias, 0.f));
        }
        if (cc < 7) {                       // prefetch next chunk's layer2 wts
#pragma unroll
            for (int nt2 = 0; nt2 < 8; ++nt2)
                p2f[nxt][nt2] = *(const short8*)(p2 + (size_t)((((ch + 1) << 3) + nt2) * 64 + lane) * 8);
        }
        const short8 a2 = *(const short8*)&h1s[s][lq][quad * 8];
#pragma unroll
        for (int nt2 = 0; nt2 < 8; ++nt2)
            c2[nt2] = __builtin_amdgcn_mfma_f32_16x16x32_bf16(a2, p2f[cur][nt2], c2[nt2], 0, 0, 0);
    }

    // ---- cross-wave c2 reduce: s=0 writes partials, s=1 finishes ----
    if (s == 0) {
#pragma unroll
        for (int nt2 = 0; nt2 < 8; ++nt2)
#pragma unroll
            for (int r = 0; r < 4; ++r)
                c2s[nt2 * 4 + r][lane] = c2[nt2][r];
    }
    __syncthreads();
    if (s == 1) {
        // vg gather (deferred): vg = v_j + pe
        f32x4 vg[8];
#pragma unroll
        for (int nt2 = 0; nt2 < 8; ++nt2) {
            int d = nt2 * 16 + lq;
#pragma unroll
            for (int r = 0; r < 4; ++r)
                vg[nt2][r] = qkv[(size_t)(b * N_PTS + jr[r]) * 384 + 256 + d] + pe[nt2][r];
        }
#pragma unroll
        for (int nt2 = 0; nt2 < 8; ++nt2) {
            f32x4 s4;
#pragma unroll
            for (int r = 0; r < 4; ++r) s4[r] = c2[nt2][r] + c2s[nt2 * 4 + r][lane];
            float m = fmaxf(fmaxf(s4[0], s4[1]), fmaxf(s4[2], s4[3]));
            m = fmaxf(m, __shfl_xor(m, 16));
            m = fmaxf(m, __shfl_xor(m, 32));
            float e0 = __expf(s4[0] - m), e1 = __expf(s4[1] - m);
            float e2 = __expf(s4[2] - m), e3 = __expf(s4[3] - m);
            float ss = e0 + e1 + e2 + e3;
            f32x4 v4 = vg[nt2];
            float a = e0 * v4[0] + e1 * v4[1] + e2 * v4[2] + e3 * v4[3];
            ss += __shfl_xor(ss, 16); ss += __shfl_xor(ss, 32);
            a  += __shfl_xor(a, 16);  a  += __shfl_xor(a, 32);
            if (quad == 0)
                out[(size_t)(b * DIM + nt2 * 16 + lq) * N_PTS + n] = a / ss;
        }
    }
}

extern "C" void kernel_launch(void* const* d_in, const int* in_sizes, int n_in,
                              void* d_out, int out_size, void* d_ws, size_t ws_size,
                              hipStream_t stream) {
    const float* x    = (const float*)d_in[0];
    const float* pos  = (const float*)d_in[1];
    const float* wqkv = (const float*)d_in[2];
    const float* pw1  = (const float*)d_in[3];
    const float* pb1  = (const float*)d_in[4];
    const float* pw2  = (const float*)d_in[5];
    const float* pb2  = (const float*)d_in[6];
    const float* aw1  = (const float*)d_in[7];
    const float* ab1  = (const float*)d_in[8];
    const float* aw2  = (const float*)d_in[9];
    // ab2 unused: softmax over k is invariant to per-channel bias.
    float* out = (float*)d_out;

    int B = in_sizes[0] / (DIM * N_PTS);
    int npts = B * N_PTS;                    // 1024

    char* ws = (char*)d_ws;
    float* qkv = (float*)ws;                               // npts*384 f32
    us* p0 = (us*)(ws + (size_t)npts * 384 * 4);           // 49152
    us* p1 = p0 + 49152;                                   // 65536
    us* p2 = p1 + 65536;                                   // 65536
    us* p3 = p2 + 65536;                                   // 8192

    pack_kernel<<<736, 256, 0, stream>>>(wqkv, aw1, aw2, pw2, p0, p1, p2, p3);
    qkv_mfma_kernel<<<npts / 16, 512, 0, stream>>>(x, p0, qkv);
    attn_fused_kernel<<<npts, 128, 0, stream>>>(pos, qkv,
                                                pw1, pb1, pb2,
                                                p1, p2, p3, ab1, out);
}